// Round 7
// baseline (127.906 us; speedup 1.0000x reference)
//
#include <hip/hip_runtime.h>

#define NN 50000
#define E0 800000
#define ET 850000          // E0 + NN self loops
#define EPS_BN 1e-5f
#define SLOPE 0.2f
#define NBP 32             // bn partial blocks
#define EPC 2048           // edges per chunk
#define NCH 416            // ceil(ET/EPC)
#define PBITS 10
#define NP 49              // partitions = ceil(NN / 1024)
#define SCN (NP*NCH)       // 20384 scan elements

__device__ __forceinline__ float lrelu(float v){ return v > 0.f ? v : SLOPE*v; }

// ---------------- K0: per-chunk partition histogram + BN partials ----------------
__global__ __launch_bounds__(256) void chunk_hist_bn(const int* __restrict__ ei, int* __restrict__ chunkcnt,
                                                     const float* __restrict__ x, float* __restrict__ part){
  __shared__ int cc[NP];
  for (int i=threadIdx.x; i<NP; i+=256) cc[i]=0;
  __syncthreads();
  int base = blockIdx.x*EPC;
  int end = min(base+EPC, ET);
  for (int e = base+threadIdx.x; e < end; e += 256){
    int dst = (e < E0) ? ei[E0 + e] : (e - E0);
    atomicAdd(&cc[dst>>PBITS], 1);
  }
  __syncthreads();
  for (int i=threadIdx.x; i<NP; i+=256) chunkcnt[blockIdx.x*NP + i] = cc[i];

  if (blockIdx.x < NBP){
    float s[4]={0,0,0,0}, q[4]={0,0,0,0};
    for (int n = blockIdx.x*256 + threadIdx.x; n < NN; n += NBP*256){
      float4 v = reinterpret_cast<const float4*>(x)[n];
      s[0]+=v.x; s[1]+=v.y; s[2]+=v.z; s[3]+=v.w;
      q[0]+=v.x*v.x; q[1]+=v.y*v.y; q[2]+=v.z*v.z; q[3]+=v.w*v.w;
    }
    #pragma unroll
    for (int m=1;m<64;m<<=1){
      #pragma unroll
      for (int i=0;i<4;i++){ s[i]+=__shfl_xor(s[i],m); q[i]+=__shfl_xor(q[i],m); }
    }
    __shared__ float lds[4][8];
    int wid = threadIdx.x>>6, lane = threadIdx.x&63;
    if (lane==0){
      #pragma unroll
      for (int i=0;i<4;i++){ lds[wid][i]=s[i]; lds[wid][4+i]=q[i]; }
    }
    __syncthreads();
    if (threadIdx.x < 8){
      float p = lds[0][threadIdx.x]+lds[1][threadIdx.x]+lds[2][threadIdx.x]+lds[3][threadIdx.x];
      part[blockIdx.x*8 + threadIdx.x] = p;
    }
  }
}

// ---------------- K1: scan of chunk counts (partition-major) + BN finalize + weight fold ----------------
__global__ __launch_bounds__(1024) void scan_fold(
    const int* __restrict__ chunkcnt, int* __restrict__ pofs,
    const float* __restrict__ part, const float* __restrict__ gamma, const float* __restrict__ beta,
    const float* __restrict__ w_e1, const float* __restrict__ as_e1, const float* __restrict__ ad_e1,
    const float* __restrict__ w_d1, const float* __restrict__ as_d1, const float* __restrict__ ad_d1,
    float* __restrict__ sclsft, float* __restrict__ fold){
  __shared__ int wsum[1024];
  int t = threadIdx.x;
  const int PER = (SCN + 1023)/1024;   // 20
  int vals[PER];
  int mysum = 0;
  #pragma unroll
  for (int k=0;k<PER;k++){
    int idx = t*PER + k;
    int v = 0;
    if (idx < SCN){ int p = idx/NCH, ch = idx - p*NCH; v = chunkcnt[ch*NP + p]; }
    vals[k] = v; mysum += v;
  }
  wsum[t] = mysum; __syncthreads();
  int val = mysum;
  for (int off=1; off<1024; off<<=1){
    int tmp = (t>=off) ? wsum[t-off] : 0;
    __syncthreads();
    val += tmp; wsum[t] = val; __syncthreads();
  }
  int run = val - mysum;   // exclusive prefix
  #pragma unroll
  for (int k=0;k<PER;k++){
    int idx = t*PER + k;
    if (idx < SCN){ int p = idx/NCH, ch = idx - p*NCH; pofs[ch*NP + p] = run; }
    run += vals[k];
  }

  if (t < 64){
    int ch = t&7, bslot = t>>3;
    float s = 0.f;
    for (int b=bslot; b<NBP; b+=8) s += part[b*8 + ch];
    s += __shfl_xor(s,8); s += __shfl_xor(s,16); s += __shfl_xor(s,32);
    float qv = __shfl(s, (t&3)+4);
    if (t < 4){
      float mu  = s*(1.0f/NN);
      float var = qv*(1.0f/NN) - mu*mu;
      float scl = rsqrtf(var + EPS_BN)*gamma[t];
      sclsft[t]   = scl;
      sclsft[4+t] = beta[t] - mu*scl;
    }
  } else if (t < 128){
    int u = t - 64;
    if (u < 32){
      int idx = u & 15; int h = idx>>2; int i = idx&3;
      const float* a = (u<16) ? as_e1 : ad_e1;
      float sum = 0.f;
      for (int c=0;c<32;c++) sum += w_e1[i*128 + h*32 + c] * a[h*32 + c];
      fold[u] = sum;
    } else if (u < 48){
      int idx = u - 32; int j = idx & 7; int h = j>>1; int i = j&1;
      const float* a = (idx<8) ? as_d1 : ad_d1;
      float sum = 0.f;
      for (int c=0;c<32;c++) sum += w_d1[i*128 + h*32 + c] * a[h*32 + c];
      fold[32 + idx] = sum;
    }
  }
}

// ---------------- K2: partition pass ----------------
__global__ __launch_bounds__(256) void partition_pass(const int* __restrict__ ei,
                                                      const int* __restrict__ pofs,
                                                      int2* __restrict__ pedge){
  __shared__ int cur[NP];
  for (int i=threadIdx.x; i<NP; i+=256) cur[i] = pofs[blockIdx.x*NP + i];
  __syncthreads();
  int base = blockIdx.x*EPC;
  int end = min(base+EPC, ET);
  for (int e = base+threadIdx.x; e < end; e += 256){
    int src, dst;
    if (e < E0){ src = ei[e]; dst = ei[E0+e]; } else { src = dst = e - E0; }
    int pos = atomicAdd(&cur[dst>>PBITS], 1);
    pedge[pos] = make_int2(src, dst);
  }
}

// ---------------- K3: per-partition LDS histogram + scan -> rowptr + exclusive-window scatter ----------------
__global__ __launch_bounds__(1024) void fine_build(const int2* __restrict__ pedge,
                                                   const int* __restrict__ pofs,
                                                   int* __restrict__ rowptr, int* __restrict__ ssrc){
  int p = blockIdx.x;
  int pstart = pofs[p];
  int pend = (p+1 < NP) ? pofs[p+1] : ET;
  int dbase = p << PBITS;
  __shared__ int hist[1<<PBITS];
  __shared__ int cur[1<<PBITS];
  int t = threadIdx.x;
  hist[t] = 0;
  __syncthreads();
  for (int i = pstart + t; i < pend; i += 1024)
    atomicAdd(&hist[pedge[i].y - dbase], 1);
  __syncthreads();
  int orig = hist[t];
  __syncthreads();
  int v = orig;
  for (int off=1; off<1024; off<<=1){
    int tmp = (t>=off) ? hist[t-off] : 0;
    __syncthreads();
    v += tmp; hist[t] = v; __syncthreads();
  }
  int excl = v - orig;
  int d = dbase + t;
  if (d < NN) rowptr[d] = pstart + excl;
  if (p == NP-1 && t == 0) rowptr[NN] = ET;
  cur[t] = pstart + excl;
  __syncthreads();
  for (int i = pstart + t; i < pend; i += 1024){
    int2 e = pedge[i];
    int pos = atomicAdd(&cur[e.y - dbase], 1);
    ssrc[pos] = e.x;
  }
}

// ---------------- node1: BN apply + layer-1 scores, packed write ----------------
// pk1[n*8]: [0..3]=als1 per head, [4..7]=xbn. ald1[n]: float4.
__global__ __launch_bounds__(256) void node1(
    const float* __restrict__ x, const float* __restrict__ sclsft, const float* __restrict__ fold,
    float* __restrict__ pk1, float* __restrict__ ald1){
  int n = blockIdx.x*256 + threadIdx.x;
  if (n >= NN) return;
  float4 v = reinterpret_cast<const float4*>(x)[n];
  float xb[4] = {v.x, v.y, v.z, v.w};
  #pragma unroll
  for (int i=0;i<4;i++) xb[i] = xb[i]*sclsft[i] + sclsft[4+i];
  float4 s4, d4;
  float* sp = &s4.x; float* dp = &d4.x;
  #pragma unroll
  for (int h=0;h<4;h++){
    float s=0.f, d=0.f;
    #pragma unroll
    for (int i=0;i<4;i++){ s += xb[i]*fold[h*4+i]; d += xb[i]*fold[16+h*4+i]; }
    sp[h]=s; dp[h]=d;
  }
  reinterpret_cast<float4*>(pk1)[n*2+0] = s4;
  reinterpret_cast<float4*>(pk1)[n*2+1] = make_float4(xb[0],xb[1],xb[2],xb[3]);
  reinterpret_cast<float4*>(ald1)[n] = d4;
}

// ---------------- eagg1: layer-1 aggregation (edge-per-lane) + fused post1 ----------------
// pk1 row: {als1[4], xbn[4]}. Writes pk2 {p0,p1,als2,0} + ald2.
__global__ __launch_bounds__(256) void eagg1(
    const float* __restrict__ pk1, const float* __restrict__ ald,
    const int* __restrict__ rowptr, const int* __restrict__ ssrc,
    const float* __restrict__ w_e1, const float* __restrict__ b_e1,
    const float* __restrict__ w_e3, const float* __restrict__ as_e3, const float* __restrict__ ad_e3,
    float* __restrict__ pk2, float* __restrict__ ald2){
  int dst = blockIdx.x*32 + (threadIdx.x>>3);
  int sub = threadIdx.x & 7;
  if (dst >= NN) return;
  int r0 = rowptr[dst], r1 = rowptr[dst+1];
  float4 advv = reinterpret_cast<const float4*>(ald)[dst];
  float adv[4] = {advv.x, advv.y, advv.z, advv.w};
  float sum[4] = {0,0,0,0};
  float acc[4][4] = {{0,0,0,0},{0,0,0,0},{0,0,0,0},{0,0,0,0}};
  for (int i = r0 + sub; i < r1; i += 8){
    int s = ssrc[i];
    float4 a = reinterpret_cast<const float4*>(pk1)[s*2+0];
    float4 f = reinterpret_cast<const float4*>(pk1)[s*2+1];
    float av[4] = {a.x,a.y,a.z,a.w};
    #pragma unroll
    for (int h=0;h<4;h++){
      float w = __expf(lrelu(av[h]+adv[h]));
      sum[h] += w;
      acc[h][0] += w*f.x; acc[h][1] += w*f.y; acc[h][2] += w*f.z; acc[h][3] += w*f.w;
    }
  }
  #pragma unroll
  for (int m=1;m<8;m<<=1){
    #pragma unroll
    for (int h=0;h<4;h++){
      sum[h] += __shfl_xor(sum[h],m);
      #pragma unroll
      for (int c=0;c<4;c++) acc[h][c] += __shfl_xor(acc[h][c],m);
    }
  }
  // head-select (branch-free): lane sub handles oc = sub*16..+15, all in head sub>>1
  int hh = sub>>1;
  float G0=acc[0][0], G1=acc[0][1], G2=acc[0][2], G3=acc[0][3], GS=sum[0];
  #pragma unroll
  for (int h=1;h<4;h++){
    if (hh==h){ G0=acc[h][0]; G1=acc[h][1]; G2=acc[h][2]; G3=acc[h][3]; GS=sum[h]; }
  }
  float ginv = 1.f/(GS+1e-16f);
  G0*=ginv; G1*=ginv; G2*=ginv; G3*=ginv;
  // enc1 for 16 oc + project to latent dims
  float p0 = 0.f, p1 = 0.f;
  int ocb = sub*16;
  #pragma unroll
  for (int q=0;q<4;q++){
    int o = ocb + q*4;
    float4 b  = *reinterpret_cast<const float4*>(b_e1 + o);
    float4 w0 = *reinterpret_cast<const float4*>(w_e1 + 0*128 + o);
    float4 w1 = *reinterpret_cast<const float4*>(w_e1 + 1*128 + o);
    float4 w2 = *reinterpret_cast<const float4*>(w_e1 + 2*128 + o);
    float4 w3 = *reinterpret_cast<const float4*>(w_e1 + 3*128 + o);
    float e0 = fmaxf(b.x + G0*w0.x + G1*w1.x + G2*w2.x + G3*w3.x, 0.f);
    float e1 = fmaxf(b.y + G0*w0.y + G1*w1.y + G2*w2.y + G3*w3.y, 0.f);
    float e2 = fmaxf(b.z + G0*w0.z + G1*w1.z + G2*w2.z + G3*w3.z, 0.f);
    float e3 = fmaxf(b.w + G0*w0.w + G1*w1.w + G2*w2.w + G3*w3.w, 0.f);
    float4 wa = *reinterpret_cast<const float4*>(w_e3 + o*2);
    float4 wb = *reinterpret_cast<const float4*>(w_e3 + o*2 + 4);
    p0 += e0*wa.x + e1*wa.z + e2*wb.x + e3*wb.z;
    p1 += e0*wa.y + e1*wa.w + e2*wb.y + e3*wb.w;
  }
  #pragma unroll
  for (int m=1;m<8;m<<=1){ p0 += __shfl_xor(p0,m); p1 += __shfl_xor(p1,m); }
  if (sub==0){
    reinterpret_cast<float4*>(pk2)[dst] = make_float4(p0, p1, p0*as_e3[0]+p1*as_e3[1], 0.f);
    ald2[dst] = p0*ad_e3[0] + p1*ad_e3[1];
  }
}

// ---------------- eagg2: layer-2 aggregation (1 head, packed float4) ----------------
// pk2 row: {h2x, h2y, als2, pad}. Writes pk3 {als3[4], l0, l1, -, -} + ald3 (float4).
__global__ __launch_bounds__(256) void eagg2(
    const float* __restrict__ pk2, const float* __restrict__ ald2,
    const int* __restrict__ rowptr, const int* __restrict__ ssrc,
    const float* __restrict__ b_e3, const float* __restrict__ fold,
    float* __restrict__ pk3, float* __restrict__ ald3){
  int dst = blockIdx.x*32 + (threadIdx.x>>3);
  int sub = threadIdx.x & 7;
  if (dst >= NN) return;
  int r0 = rowptr[dst], r1 = rowptr[dst+1];
  float adv = ald2[dst];
  float sum = 0.f, a0 = 0.f, a1 = 0.f;
  for (int i = r0 + sub; i < r1; i += 8){
    int s = ssrc[i];
    float4 r = reinterpret_cast<const float4*>(pk2)[s];
    float w = __expf(lrelu(r.z + adv));
    sum += w; a0 += w*r.x; a1 += w*r.y;
  }
  #pragma unroll
  for (int m=1;m<8;m<<=1){
    sum += __shfl_xor(sum,m); a0 += __shfl_xor(a0,m); a1 += __shfl_xor(a1,m);
  }
  if (sub != 0) return;
  float inv = 1.f/(sum+1e-16f);
  float l0 = a0*inv + b_e3[0];
  float l1 = a1*inv + b_e3[1];
  float4 s3, d3; float* sp=&s3.x; float* dp=&d3.x;
  #pragma unroll
  for (int h=0;h<4;h++){
    sp[h] = l0*fold[32+h*2+0] + l1*fold[32+h*2+1];
    dp[h] = l0*fold[40+h*2+0] + l1*fold[40+h*2+1];
  }
  reinterpret_cast<float4*>(pk3)[dst*2] = s3;
  pk3[(size_t)dst*8+4] = l0;
  pk3[(size_t)dst*8+5] = l1;
  reinterpret_cast<float4*>(ald3)[dst] = d3;
}

// ---------------- eagg3: layer-3 aggregation (edge-per-lane) + fused post3 ----------------
// pk3 row: {als3[4], l0, l1, -, -}. Writes feat4 {h4[4]} + s4 (als4) + ald4.
__global__ __launch_bounds__(256) void eagg3(
    const float* __restrict__ pk3, const float* __restrict__ ald3,
    const int* __restrict__ rowptr, const int* __restrict__ ssrc,
    const float* __restrict__ w_d1, const float* __restrict__ b_d1,
    const float* __restrict__ w_d3, const float* __restrict__ as_d3, const float* __restrict__ ad_d3,
    float4* __restrict__ feat4, float* __restrict__ s4a, float* __restrict__ ald4){
  int dst = blockIdx.x*32 + (threadIdx.x>>3);
  int sub = threadIdx.x & 7;
  if (dst >= NN) return;
  int r0 = rowptr[dst], r1 = rowptr[dst+1];
  float4 advv = reinterpret_cast<const float4*>(ald3)[dst];
  float adv[4] = {advv.x, advv.y, advv.z, advv.w};
  float sum[4] = {0,0,0,0};
  float acc[4][2] = {{0,0},{0,0},{0,0},{0,0}};
  for (int i = r0 + sub; i < r1; i += 8){
    int s = ssrc[i];
    float4 a = reinterpret_cast<const float4*>(pk3)[s*2+0];
    float2 f = *reinterpret_cast<const float2*>(pk3 + (size_t)s*8 + 4);
    float av[4] = {a.x,a.y,a.z,a.w};
    #pragma unroll
    for (int h=0;h<4;h++){
      float w = __expf(lrelu(av[h]+adv[h]));
      sum[h] += w;
      acc[h][0] += w*f.x; acc[h][1] += w*f.y;
    }
  }
  #pragma unroll
  for (int m=1;m<8;m<<=1){
    #pragma unroll
    for (int h=0;h<4;h++){
      sum[h] += __shfl_xor(sum[h],m);
      acc[h][0] += __shfl_xor(acc[h][0],m);
      acc[h][1] += __shfl_xor(acc[h][1],m);
    }
  }
  int hh = sub>>1;
  float G0=acc[0][0], G1=acc[0][1], GS=sum[0];
  #pragma unroll
  for (int h=1;h<4;h++){
    if (hh==h){ G0=acc[h][0]; G1=acc[h][1]; GS=sum[h]; }
  }
  float ginv = 1.f/(GS+1e-16f);
  G0*=ginv; G1*=ginv;
  float p0=0.f,p1=0.f,p2=0.f,p3=0.f;
  int ocb = sub*16;
  #pragma unroll
  for (int q=0;q<4;q++){
    int o = ocb + q*4;
    float4 b  = *reinterpret_cast<const float4*>(b_d1 + o);
    float4 w0 = *reinterpret_cast<const float4*>(w_d1 + 0*128 + o);
    float4 w1 = *reinterpret_cast<const float4*>(w_d1 + 1*128 + o);
    float e0 = fmaxf(b.x + G0*w0.x + G1*w1.x, 0.f);
    float e1 = fmaxf(b.y + G0*w0.y + G1*w1.y, 0.f);
    float e2 = fmaxf(b.z + G0*w0.z + G1*w1.z, 0.f);
    float e3 = fmaxf(b.w + G0*w0.w + G1*w1.w, 0.f);
    float4 d0 = *reinterpret_cast<const float4*>(w_d3 + (o+0)*4);
    float4 d1 = *reinterpret_cast<const float4*>(w_d3 + (o+1)*4);
    float4 d2 = *reinterpret_cast<const float4*>(w_d3 + (o+2)*4);
    float4 d3v = *reinterpret_cast<const float4*>(w_d3 + (o+3)*4);
    p0 += e0*d0.x + e1*d1.x + e2*d2.x + e3*d3v.x;
    p1 += e0*d0.y + e1*d1.y + e2*d2.y + e3*d3v.y;
    p2 += e0*d0.z + e1*d1.z + e2*d2.z + e3*d3v.z;
    p3 += e0*d0.w + e1*d1.w + e2*d2.w + e3*d3v.w;
  }
  #pragma unroll
  for (int m=1;m<8;m<<=1){
    p0 += __shfl_xor(p0,m); p1 += __shfl_xor(p1,m);
    p2 += __shfl_xor(p2,m); p3 += __shfl_xor(p3,m);
  }
  if (sub==0){
    feat4[dst] = make_float4(p0,p1,p2,p3);
    s4a[dst]  = p0*as_d3[0]+p1*as_d3[1]+p2*as_d3[2]+p3*as_d3[3];
    ald4[dst] = p0*ad_d3[0]+p1*ad_d3[1]+p2*ad_d3[2]+p3*ad_d3[3];
  }
}

// ---------------- eagg4: layer-4 aggregation (1 head) -> output ----------------
__global__ __launch_bounds__(256) void eagg4(
    const float4* __restrict__ feat4, const float* __restrict__ s4a, const float* __restrict__ ald4,
    const int* __restrict__ rowptr, const int* __restrict__ ssrc,
    const float* __restrict__ b_d3, float* __restrict__ out){
  int dst = blockIdx.x*32 + (threadIdx.x>>3);
  int sub = threadIdx.x & 7;
  if (dst >= NN) return;
  int r0 = rowptr[dst], r1 = rowptr[dst+1];
  float adv = ald4[dst];
  float sum = 0.f, a0=0.f, a1=0.f, a2=0.f, a3=0.f;
  for (int i = r0 + sub; i < r1; i += 8){
    int s = ssrc[i];
    float w = __expf(lrelu(s4a[s] + adv));
    float4 f = feat4[s];
    sum += w; a0 += w*f.x; a1 += w*f.y; a2 += w*f.z; a3 += w*f.w;
  }
  #pragma unroll
  for (int m=1;m<8;m<<=1){
    sum += __shfl_xor(sum,m);
    a0 += __shfl_xor(a0,m); a1 += __shfl_xor(a1,m);
    a2 += __shfl_xor(a2,m); a3 += __shfl_xor(a3,m);
  }
  if (sub != 0) return;
  float inv = 1.f/(sum+1e-16f);
  reinterpret_cast<float4*>(out)[dst] =
    make_float4(a0*inv+b_d3[0], a1*inv+b_d3[1], a2*inv+b_d3[2], a3*inv+b_d3[3]);
}

// ---------------- launch ----------------
extern "C" void kernel_launch(void* const* d_in, const int* in_sizes, int n_in,
                              void* d_out, int out_size, void* d_ws, size_t ws_size,
                              hipStream_t stream) {
  const float* x     = (const float*)d_in[0];
  const int*   ei    = (const int*)  d_in[1];
  const float* gamma = (const float*)d_in[2];
  const float* beta  = (const float*)d_in[3];
  const float* w_e1  = (const float*)d_in[4];
  const float* as_e1 = (const float*)d_in[5];
  const float* ad_e1 = (const float*)d_in[6];
  const float* b_e1  = (const float*)d_in[7];
  const float* w_e3  = (const float*)d_in[8];
  const float* as_e3 = (const float*)d_in[9];
  const float* ad_e3 = (const float*)d_in[10];
  const float* b_e3  = (const float*)d_in[11];
  const float* w_d1  = (const float*)d_in[12];
  const float* as_d1 = (const float*)d_in[13];
  const float* ad_d1 = (const float*)d_in[14];
  const float* b_d1  = (const float*)d_in[15];
  const float* w_d3  = (const float*)d_in[16];
  const float* as_d3 = (const float*)d_in[17];
  const float* ad_d3 = (const float*)d_in[18];
  const float* b_d3  = (const float*)d_in[19];

  char* ws = (char*)d_ws;
  size_t off = 0;
  auto alloc = [&](size_t bytes)->void*{
    void* p = ws + off;
    off += (bytes + 255) & ~(size_t)255;
    return p;
  };
  int*   chunkcnt = (int*)  alloc((size_t)NCH*NP*4);
  int*   pofs     = (int*)  alloc((size_t)NCH*NP*4);
  int2*  pedge    = (int2*) alloc((size_t)ET*8);
  int*   rowptr   = (int*)  alloc((size_t)(NN+1)*4);
  int*   ssrc     = (int*)  alloc((size_t)ET*4);
  float* part     = (float*)alloc((size_t)NBP*8*4);
  float* sclsft   = (float*)alloc(32);
  float* fold     = (float*)alloc(64*4);
  float* pk1      = (float*)alloc((size_t)NN*8*4);
  float* ald1     = (float*)alloc((size_t)NN*4*4);
  float* pk2      = (float*)alloc((size_t)NN*4*4);
  float* ald2     = (float*)alloc((size_t)NN*4);
  float* pk3      = (float*)alloc((size_t)NN*8*4);
  float* ald3     = (float*)alloc((size_t)NN*4*4);
  float4* feat4   = (float4*)alloc((size_t)NN*4*4);
  float* s4a      = (float*)alloc((size_t)NN*4);
  float* ald4     = (float*)alloc((size_t)NN*4);

  // CSR build: deterministic two-level counting sort, block-exclusive write regions
  chunk_hist_bn<<<NCH, 256, 0, stream>>>(ei, chunkcnt, x, part);
  scan_fold<<<1, 1024, 0, stream>>>(chunkcnt, pofs, part, gamma, beta,
                                    w_e1, as_e1, ad_e1, w_d1, as_d1, ad_d1, sclsft, fold);
  partition_pass<<<NCH, 256, 0, stream>>>(ei, pofs, pedge);
  fine_build<<<NP, 1024, 0, stream>>>(pedge, pofs, rowptr, ssrc);

  const int AGG_BLOCKS = (NN+31)/32;

  node1<<<(NN+255)/256, 256, 0, stream>>>(x, sclsft, fold, pk1, ald1);
  eagg1<<<AGG_BLOCKS, 256, 0, stream>>>(pk1, ald1, rowptr, ssrc,
                                        w_e1, b_e1, w_e3, as_e3, ad_e3, pk2, ald2);
  eagg2<<<AGG_BLOCKS, 256, 0, stream>>>(pk2, ald2, rowptr, ssrc, b_e3, fold, pk3, ald3);
  eagg3<<<AGG_BLOCKS, 256, 0, stream>>>(pk3, ald3, rowptr, ssrc,
                                        w_d1, b_d1, w_d3, as_d3, ad_d3, feat4, s4a, ald4);
  eagg4<<<AGG_BLOCKS, 256, 0, stream>>>(feat4, s4a, ald4, rowptr, ssrc, b_d3, (float*)d_out);
}

// Round 8
// 124.115 us; speedup vs baseline: 1.0305x; 1.0305x over previous
//
#include <hip/hip_runtime.h>

#define NN 50000
#define E0 800000
#define ET 850000          // E0 + NN self loops
#define EPS_BN 1e-5f
#define SLOPE 0.2f
#define NBP 32             // bn partial blocks
#define EPC 8192           // edges per chunk
#define NCH 104            // ceil(ET/EPC)
#define PBITS 9
#define NP 98              // partitions = ceil(NN/512)
#define SCN (NP*NCH)       // 10192 scan elements

__device__ __forceinline__ float lrelu(float v){ return v > 0.f ? v : SLOPE*v; }

// ---------------- K0: per-chunk partition histogram + BN partials ----------------
__global__ __launch_bounds__(1024) void chunk_hist_bn(const int* __restrict__ ei, int* __restrict__ chunkcnt,
                                                      const float* __restrict__ x, float* __restrict__ part){
  __shared__ int cc[NP];
  int t = threadIdx.x;
  for (int i=t; i<NP; i+=1024) cc[i]=0;
  __syncthreads();
  int base = blockIdx.x*EPC;
  int end = min(base+EPC, ET);
  for (int e = base+t; e < end; e += 1024){
    int dst = (e < E0) ? ei[E0 + e] : (e - E0);
    atomicAdd(&cc[dst>>PBITS], 1);
  }
  __syncthreads();
  for (int i=t; i<NP; i+=1024) chunkcnt[blockIdx.x*NP + i] = cc[i];

  if (blockIdx.x < NBP){
    float s[4]={0,0,0,0}, q[4]={0,0,0,0};
    for (int n = blockIdx.x*1024 + t; n < NN; n += NBP*1024){
      float4 v = reinterpret_cast<const float4*>(x)[n];
      s[0]+=v.x; s[1]+=v.y; s[2]+=v.z; s[3]+=v.w;
      q[0]+=v.x*v.x; q[1]+=v.y*v.y; q[2]+=v.z*v.z; q[3]+=v.w*v.w;
    }
    #pragma unroll
    for (int m=1;m<64;m<<=1){
      #pragma unroll
      for (int i=0;i<4;i++){ s[i]+=__shfl_xor(s[i],m); q[i]+=__shfl_xor(q[i],m); }
    }
    __shared__ float lds[16][8];
    int wid = t>>6, lane = t&63;
    if (lane==0){
      #pragma unroll
      for (int i=0;i<4;i++){ lds[wid][i]=s[i]; lds[wid][4+i]=q[i]; }
    }
    __syncthreads();
    if (t < 8){
      float p = 0.f;
      #pragma unroll
      for (int w=0;w<16;w++) p += lds[w][t];
      part[blockIdx.x*8 + t] = p;
    }
  }
}

// ---------------- K1: scan (partition-major) + BN finalize + weight fold ----------------
// pofs[ch*NP+p] = global offset of (chunk ch, partition p) run in pedge.
// sclsft[0..3]=scale, [4..7]=shift
// fold[0:16) ws1[h*4+i]  fold[16:32) wd1[h*4+i]  fold[32:40) ws3[h*2+i]  fold[40:48) wd3[h*2+i]
__global__ __launch_bounds__(1024) void scan_fold(
    const int* __restrict__ chunkcnt, int* __restrict__ pofs,
    const float* __restrict__ part, const float* __restrict__ gamma, const float* __restrict__ beta,
    const float* __restrict__ w_e1, const float* __restrict__ as_e1, const float* __restrict__ ad_e1,
    const float* __restrict__ w_d1, const float* __restrict__ as_d1, const float* __restrict__ ad_d1,
    float* __restrict__ sclsft, float* __restrict__ fold){
  __shared__ int wsum[1024];
  int t = threadIdx.x;
  const int PER = (SCN + 1023)/1024;   // 10
  int vals[PER];
  int mysum = 0;
  #pragma unroll
  for (int k=0;k<PER;k++){
    int idx = t*PER + k;
    int v = 0;
    if (idx < SCN){ int p = idx/NCH, ch = idx - p*NCH; v = chunkcnt[ch*NP + p]; }
    vals[k] = v; mysum += v;
  }
  wsum[t] = mysum; __syncthreads();
  int val = mysum;
  for (int off=1; off<1024; off<<=1){
    int tmp = (t>=off) ? wsum[t-off] : 0;
    __syncthreads();
    val += tmp; wsum[t] = val; __syncthreads();
  }
  int run = val - mysum;   // exclusive prefix
  #pragma unroll
  for (int k=0;k<PER;k++){
    int idx = t*PER + k;
    if (idx < SCN){ int p = idx/NCH, ch = idx - p*NCH; pofs[ch*NP + p] = run; }
    run += vals[k];
  }

  if (t < 64){
    int ch = t&7, bslot = t>>3;
    float s = 0.f;
    for (int b=bslot; b<NBP; b+=8) s += part[b*8 + ch];
    s += __shfl_xor(s,8); s += __shfl_xor(s,16); s += __shfl_xor(s,32);
    float qv = __shfl(s, (t&3)+4);
    if (t < 4){
      float mu  = s*(1.0f/NN);
      float var = qv*(1.0f/NN) - mu*mu;
      float scl = rsqrtf(var + EPS_BN)*gamma[t];
      sclsft[t]   = scl;
      sclsft[4+t] = beta[t] - mu*scl;
    }
  } else if (t < 128){
    int u = t - 64;
    if (u < 32){
      int idx = u & 15; int h = idx>>2; int i = idx&3;
      const float* a = (u<16) ? as_e1 : ad_e1;
      float sum = 0.f;
      for (int c=0;c<32;c++) sum += w_e1[i*128 + h*32 + c] * a[h*32 + c];
      fold[u] = sum;
    } else if (u < 48){
      int idx = u - 32; int j = idx & 7; int h = j>>1; int i = j&1;
      const float* a = (idx<8) ? as_d1 : ad_d1;
      float sum = 0.f;
      for (int c=0;c<32;c++) sum += w_d1[i*128 + h*32 + c] * a[h*32 + c];
      fold[32 + idx] = sum;
    }
  }
}

// ---------------- K2: partition pass ----------------
__global__ __launch_bounds__(1024) void partition_pass(const int* __restrict__ ei,
                                                       const int* __restrict__ pofs,
                                                       int2* __restrict__ pedge){
  __shared__ int cur[NP];
  int t = threadIdx.x;
  for (int i=t; i<NP; i+=1024) cur[i] = pofs[blockIdx.x*NP + i];
  __syncthreads();
  int base = blockIdx.x*EPC;
  int end = min(base+EPC, ET);
  for (int e = base+t; e < end; e += 1024){
    int src, dst;
    if (e < E0){ src = ei[e]; dst = ei[E0+e]; } else { src = dst = e - E0; }
    int pos = atomicAdd(&cur[dst>>PBITS], 1);
    pedge[pos] = make_int2(src, dst);
  }
}

// ---------------- K3: per-partition LDS hist + scan -> rowptr + exclusive-window scatter ----------------
__global__ __launch_bounds__(1024) void fine_build(const int2* __restrict__ pedge,
                                                   const int* __restrict__ pofs,
                                                   int* __restrict__ rowptr, int* __restrict__ ssrc){
  int p = blockIdx.x;
  int pstart = pofs[p];
  int pend = (p+1 < NP) ? pofs[p+1] : ET;
  int dbase = p << PBITS;
  __shared__ int hist[1<<PBITS];
  __shared__ int cur[1<<PBITS];
  int t = threadIdx.x;
  if (t < 512) hist[t] = 0;
  __syncthreads();
  for (int i = pstart + t; i < pend; i += 1024)
    atomicAdd(&hist[pedge[i].y - dbase], 1);
  __syncthreads();
  int orig = (t < 512) ? hist[t] : 0;
  __syncthreads();
  int v = orig;
  for (int off=1; off<512; off<<=1){
    int tmp = (t>=off && t<512) ? hist[t-off] : 0;
    __syncthreads();
    if (t < 512){ v += tmp; hist[t] = v; }
    __syncthreads();
  }
  if (t < 512){
    int excl = v - orig;
    int d = dbase + t;
    if (d < NN) rowptr[d] = pstart + excl;
    if (p == NP-1 && t == 0) rowptr[NN] = ET;
    cur[t] = pstart + excl;
  }
  __syncthreads();
  for (int i = pstart + t; i < pend; i += 1024){
    int2 e = pedge[i];
    int pos = atomicAdd(&cur[e.y - dbase], 1);
    ssrc[pos] = e.x;
  }
}

// ---------------- eagg1: layer-1 (BN + scores recomputed per edge) + fused post1 ----------------
// Gathers raw x[src]; writes pk2 {p0,p1} only.
__global__ __launch_bounds__(256) void eagg1(
    const float* __restrict__ x, const float* __restrict__ sclsft, const float* __restrict__ fold,
    const int* __restrict__ rowptr, const int* __restrict__ ssrc,
    const float* __restrict__ w_e1, const float* __restrict__ b_e1, const float* __restrict__ w_e3,
    float2* __restrict__ pk2){
  int dst = blockIdx.x*64 + (threadIdx.x>>2);
  int sub = threadIdx.x & 3;
  if (dst >= NN) return;
  float sc[8];
  #pragma unroll
  for (int i=0;i<8;i++) sc[i] = sclsft[i];
  float fs[16];
  #pragma unroll
  for (int i=0;i<16;i++) fs[i] = fold[i];
  // dst-side score
  float4 xd = reinterpret_cast<const float4*>(x)[dst];
  float xbd[4] = {xd.x*sc[0]+sc[4], xd.y*sc[1]+sc[5], xd.z*sc[2]+sc[6], xd.w*sc[3]+sc[7]};
  float ald[4];
  #pragma unroll
  for (int h=0;h<4;h++)
    ald[h] = xbd[0]*fold[16+h*4+0] + xbd[1]*fold[16+h*4+1]
           + xbd[2]*fold[16+h*4+2] + xbd[3]*fold[16+h*4+3];
  int r0 = rowptr[dst], r1 = rowptr[dst+1];
  float sum[4] = {0,0,0,0};
  float acc[4][4] = {{0,0,0,0},{0,0,0,0},{0,0,0,0},{0,0,0,0}};
  for (int i = r0 + sub; i < r1; i += 4){
    int s = ssrc[i];
    float4 xs = reinterpret_cast<const float4*>(x)[s];
    float xb[4] = {xs.x*sc[0]+sc[4], xs.y*sc[1]+sc[5], xs.z*sc[2]+sc[6], xs.w*sc[3]+sc[7]};
    #pragma unroll
    for (int h=0;h<4;h++){
      float a = xb[0]*fs[h*4+0] + xb[1]*fs[h*4+1] + xb[2]*fs[h*4+2] + xb[3]*fs[h*4+3];
      float w = __expf(lrelu(a + ald[h]));
      sum[h] += w;
      acc[h][0] += w*xb[0]; acc[h][1] += w*xb[1]; acc[h][2] += w*xb[2]; acc[h][3] += w*xb[3];
    }
  }
  #pragma unroll
  for (int m=1;m<4;m<<=1){
    #pragma unroll
    for (int h=0;h<4;h++){
      sum[h] += __shfl_xor(sum[h],m);
      #pragma unroll
      for (int c=0;c<4;c++) acc[h][c] += __shfl_xor(acc[h][c],m);
    }
  }
  // lane sub owns head sub (oc = sub*32 .. +31)
  float G0=acc[0][0], G1=acc[0][1], G2=acc[0][2], G3=acc[0][3], GS=sum[0];
  #pragma unroll
  for (int h=1;h<4;h++){
    if (sub==h){ G0=acc[h][0]; G1=acc[h][1]; G2=acc[h][2]; G3=acc[h][3]; GS=sum[h]; }
  }
  float inv = 1.f/(GS+1e-16f);
  G0*=inv; G1*=inv; G2*=inv; G3*=inv;
  float p0 = 0.f, p1 = 0.f;
  int ob = sub*32;
  #pragma unroll
  for (int q=0;q<8;q++){
    int o = ob + q*4;
    float4 b  = *reinterpret_cast<const float4*>(b_e1 + o);
    float4 w0 = *reinterpret_cast<const float4*>(w_e1 + 0*128 + o);
    float4 w1 = *reinterpret_cast<const float4*>(w_e1 + 1*128 + o);
    float4 w2 = *reinterpret_cast<const float4*>(w_e1 + 2*128 + o);
    float4 w3 = *reinterpret_cast<const float4*>(w_e1 + 3*128 + o);
    float e0 = fmaxf(b.x + G0*w0.x + G1*w1.x + G2*w2.x + G3*w3.x, 0.f);
    float e1 = fmaxf(b.y + G0*w0.y + G1*w1.y + G2*w2.y + G3*w3.y, 0.f);
    float e2 = fmaxf(b.z + G0*w0.z + G1*w1.z + G2*w2.z + G3*w3.z, 0.f);
    float e3 = fmaxf(b.w + G0*w0.w + G1*w1.w + G2*w2.w + G3*w3.w, 0.f);
    float4 wa = *reinterpret_cast<const float4*>(w_e3 + o*2);
    float4 wb = *reinterpret_cast<const float4*>(w_e3 + o*2 + 4);
    p0 += e0*wa.x + e1*wa.z + e2*wb.x + e3*wb.z;
    p1 += e0*wa.y + e1*wa.w + e2*wb.y + e3*wb.w;
  }
  p0 += __shfl_xor(p0,1); p0 += __shfl_xor(p0,2);
  p1 += __shfl_xor(p1,1); p1 += __shfl_xor(p1,2);
  if (sub==0) pk2[dst] = make_float2(p0, p1);
}

// ---------------- eagg2: layer-2 (scores recomputed from pk2) ----------------
// Gathers pk2 {p0,p1}; writes lat2 {l0,l1}.
__global__ __launch_bounds__(256) void eagg2(
    const float2* __restrict__ pk2,
    const int* __restrict__ rowptr, const int* __restrict__ ssrc,
    const float* __restrict__ as_e3, const float* __restrict__ ad_e3, const float* __restrict__ b_e3,
    float2* __restrict__ lat2){
  int dst = blockIdx.x*64 + (threadIdx.x>>2);
  int sub = threadIdx.x & 3;
  if (dst >= NN) return;
  float as0 = as_e3[0], as1 = as_e3[1];
  float2 pd = pk2[dst];
  float adv = pd.x*ad_e3[0] + pd.y*ad_e3[1];
  int r0 = rowptr[dst], r1 = rowptr[dst+1];
  float sum = 0.f, a0 = 0.f, a1 = 0.f;
  for (int i = r0 + sub; i < r1; i += 4){
    int s = ssrc[i];
    float2 p = pk2[s];
    float w = __expf(lrelu(p.x*as0 + p.y*as1 + adv));
    sum += w; a0 += w*p.x; a1 += w*p.y;
  }
  #pragma unroll
  for (int m=1;m<4;m<<=1){
    sum += __shfl_xor(sum,m); a0 += __shfl_xor(a0,m); a1 += __shfl_xor(a1,m);
  }
  if (sub==0){
    float inv = 1.f/(sum+1e-16f);
    lat2[dst] = make_float2(a0*inv + b_e3[0], a1*inv + b_e3[1]);
  }
}

// ---------------- eagg3: layer-3 (scores recomputed from lat2 via fold) + fused post3 ----------------
// Gathers lat2 {l0,l1}; writes pk4 {h4[4]}.
__global__ __launch_bounds__(256) void eagg3(
    const float2* __restrict__ lat2, const float* __restrict__ fold,
    const int* __restrict__ rowptr, const int* __restrict__ ssrc,
    const float* __restrict__ w_d1, const float* __restrict__ b_d1, const float* __restrict__ w_d3,
    float4* __restrict__ pk4){
  int dst = blockIdx.x*64 + (threadIdx.x>>2);
  int sub = threadIdx.x & 3;
  if (dst >= NN) return;
  float f3[8];
  #pragma unroll
  for (int i=0;i<8;i++) f3[i] = fold[32+i];
  float2 ld = lat2[dst];
  float ald[4];
  #pragma unroll
  for (int h=0;h<4;h++) ald[h] = ld.x*fold[40+h*2+0] + ld.y*fold[40+h*2+1];
  int r0 = rowptr[dst], r1 = rowptr[dst+1];
  float sum[4] = {0,0,0,0};
  float acc[4][2] = {{0,0},{0,0},{0,0},{0,0}};
  for (int i = r0 + sub; i < r1; i += 4){
    int s = ssrc[i];
    float2 l = lat2[s];
    #pragma unroll
    for (int h=0;h<4;h++){
      float a = l.x*f3[h*2+0] + l.y*f3[h*2+1];
      float w = __expf(lrelu(a + ald[h]));
      sum[h] += w;
      acc[h][0] += w*l.x; acc[h][1] += w*l.y;
    }
  }
  #pragma unroll
  for (int m=1;m<4;m<<=1){
    #pragma unroll
    for (int h=0;h<4;h++){
      sum[h] += __shfl_xor(sum[h],m);
      acc[h][0] += __shfl_xor(acc[h][0],m);
      acc[h][1] += __shfl_xor(acc[h][1],m);
    }
  }
  float G0=acc[0][0], G1=acc[0][1], GS=sum[0];
  #pragma unroll
  for (int h=1;h<4;h++){
    if (sub==h){ G0=acc[h][0]; G1=acc[h][1]; GS=sum[h]; }
  }
  float inv = 1.f/(GS+1e-16f);
  G0*=inv; G1*=inv;
  float p0=0.f,p1=0.f,p2=0.f,p3=0.f;
  int ob = sub*32;
  #pragma unroll
  for (int q=0;q<8;q++){
    int o = ob + q*4;
    float4 b  = *reinterpret_cast<const float4*>(b_d1 + o);
    float4 w0 = *reinterpret_cast<const float4*>(w_d1 + 0*128 + o);
    float4 w1 = *reinterpret_cast<const float4*>(w_d1 + 1*128 + o);
    float e0 = fmaxf(b.x + G0*w0.x + G1*w1.x, 0.f);
    float e1 = fmaxf(b.y + G0*w0.y + G1*w1.y, 0.f);
    float e2 = fmaxf(b.z + G0*w0.z + G1*w1.z, 0.f);
    float e3 = fmaxf(b.w + G0*w0.w + G1*w1.w, 0.f);
    float4 d0 = *reinterpret_cast<const float4*>(w_d3 + (o+0)*4);
    float4 d1 = *reinterpret_cast<const float4*>(w_d3 + (o+1)*4);
    float4 d2 = *reinterpret_cast<const float4*>(w_d3 + (o+2)*4);
    float4 d3v= *reinterpret_cast<const float4*>(w_d3 + (o+3)*4);
    p0 += e0*d0.x + e1*d1.x + e2*d2.x + e3*d3v.x;
    p1 += e0*d0.y + e1*d1.y + e2*d2.y + e3*d3v.y;
    p2 += e0*d0.z + e1*d1.z + e2*d2.z + e3*d3v.z;
    p3 += e0*d0.w + e1*d1.w + e2*d2.w + e3*d3v.w;
  }
  #pragma unroll
  for (int m=1;m<4;m<<=1){
    p0 += __shfl_xor(p0,m); p1 += __shfl_xor(p1,m);
    p2 += __shfl_xor(p2,m); p3 += __shfl_xor(p3,m);
  }
  if (sub==0) pk4[dst] = make_float4(p0,p1,p2,p3);
}

// ---------------- eagg4: layer-4 (scores recomputed from pk4) -> output ----------------
__global__ __launch_bounds__(256) void eagg4(
    const float4* __restrict__ pk4,
    const int* __restrict__ rowptr, const int* __restrict__ ssrc,
    const float* __restrict__ as_d3, const float* __restrict__ ad_d3, const float* __restrict__ b_d3,
    float* __restrict__ out){
  int dst = blockIdx.x*64 + (threadIdx.x>>2);
  int sub = threadIdx.x & 3;
  if (dst >= NN) return;
  float as0=as_d3[0], as1=as_d3[1], as2=as_d3[2], as3=as_d3[3];
  float4 hd = pk4[dst];
  float adv = hd.x*ad_d3[0] + hd.y*ad_d3[1] + hd.z*ad_d3[2] + hd.w*ad_d3[3];
  int r0 = rowptr[dst], r1 = rowptr[dst+1];
  float sum = 0.f, a0=0.f, a1=0.f, a2=0.f, a3=0.f;
  for (int i = r0 + sub; i < r1; i += 4){
    int s = ssrc[i];
    float4 f = pk4[s];
    float w = __expf(lrelu(f.x*as0 + f.y*as1 + f.z*as2 + f.w*as3 + adv));
    sum += w; a0 += w*f.x; a1 += w*f.y; a2 += w*f.z; a3 += w*f.w;
  }
  #pragma unroll
  for (int m=1;m<4;m<<=1){
    sum += __shfl_xor(sum,m);
    a0 += __shfl_xor(a0,m); a1 += __shfl_xor(a1,m);
    a2 += __shfl_xor(a2,m); a3 += __shfl_xor(a3,m);
  }
  if (sub==0){
    float inv = 1.f/(sum+1e-16f);
    reinterpret_cast<float4*>(out)[dst] =
      make_float4(a0*inv+b_d3[0], a1*inv+b_d3[1], a2*inv+b_d3[2], a3*inv+b_d3[3]);
  }
}

// ---------------- launch ----------------
extern "C" void kernel_launch(void* const* d_in, const int* in_sizes, int n_in,
                              void* d_out, int out_size, void* d_ws, size_t ws_size,
                              hipStream_t stream) {
  const float* x     = (const float*)d_in[0];
  const int*   ei    = (const int*)  d_in[1];
  const float* gamma = (const float*)d_in[2];
  const float* beta  = (const float*)d_in[3];
  const float* w_e1  = (const float*)d_in[4];
  const float* as_e1 = (const float*)d_in[5];
  const float* ad_e1 = (const float*)d_in[6];
  const float* b_e1  = (const float*)d_in[7];
  const float* w_e3  = (const float*)d_in[8];
  const float* as_e3 = (const float*)d_in[9];
  const float* ad_e3 = (const float*)d_in[10];
  const float* b_e3  = (const float*)d_in[11];
  const float* w_d1  = (const float*)d_in[12];
  const float* as_d1 = (const float*)d_in[13];
  const float* ad_d1 = (const float*)d_in[14];
  const float* b_d1  = (const float*)d_in[15];
  const float* w_d3  = (const float*)d_in[16];
  const float* as_d3 = (const float*)d_in[17];
  const float* ad_d3 = (const float*)d_in[18];
  const float* b_d3  = (const float*)d_in[19];

  char* ws = (char*)d_ws;
  size_t off = 0;
  auto alloc = [&](size_t bytes)->void*{
    void* p = ws + off;
    off += (bytes + 255) & ~(size_t)255;
    return p;
  };
  int*    chunkcnt = (int*)   alloc((size_t)SCN*4);
  int*    pofs     = (int*)   alloc((size_t)SCN*4);
  int2*   pedge    = (int2*)  alloc((size_t)ET*8);
  int*    rowptr   = (int*)   alloc((size_t)(NN+1)*4);
  int*    ssrc     = (int*)   alloc((size_t)ET*4);
  float*  part     = (float*) alloc((size_t)NBP*8*4);
  float*  sclsft   = (float*) alloc(32);
  float*  fold     = (float*) alloc(64*4);
  float2* pk2      = (float2*)alloc((size_t)NN*8);
  float2* lat2     = (float2*)alloc((size_t)NN*8);
  float4* pk4      = (float4*)alloc((size_t)NN*16);

  // CSR build: deterministic two-level counting sort, block-exclusive write regions
  chunk_hist_bn<<<NCH, 1024, 0, stream>>>(ei, chunkcnt, x, part);
  scan_fold<<<1, 1024, 0, stream>>>(chunkcnt, pofs, part, gamma, beta,
                                    w_e1, as_e1, ad_e1, w_d1, as_d1, ad_d1, sclsft, fold);
  partition_pass<<<NCH, 1024, 0, stream>>>(ei, pofs, pedge);
  fine_build<<<NP, 1024, 0, stream>>>(pedge, pofs, rowptr, ssrc);

  const int NAGG = (NN + 63)/64;   // 64 dst per 256-thread block (4 lanes/dst)

  eagg1<<<NAGG, 256, 0, stream>>>(x, sclsft, fold, rowptr, ssrc, w_e1, b_e1, w_e3, pk2);
  eagg2<<<NAGG, 256, 0, stream>>>(pk2, rowptr, ssrc, as_e3, ad_e3, b_e3, lat2);
  eagg3<<<NAGG, 256, 0, stream>>>(lat2, fold, rowptr, ssrc, w_d1, b_d1, w_d3, pk4);
  eagg4<<<NAGG, 256, 0, stream>>>(pk4, rowptr, ssrc, as_d3, ad_d3, b_d3, (float*)d_out);
}